// Round 4
// baseline (1463.758 us; speedup 1.0000x reference)
//
#include <hip/hip_runtime.h>
#include <math.h>

#define NN 100000
#define NE 1600000
#define NBKT 391                       // ceil(NN/256) buckets of 256 nodes
#define CHUNK 8192
#define NB1 ((NE + CHUNK - 1) / CHUNK) // 196 blocks

// ---------- phase 0: coarse bucket histogram (LDS-privatized) ----------
__global__ __launch_bounds__(256) void p0_hist_kernel(const int* __restrict__ dst,
                                                      int* __restrict__ bcnt) {
    __shared__ int h[NBKT];
    for (int b = threadIdx.x; b < NBKT; b += 256) h[b] = 0;
    __syncthreads();
    int e0 = blockIdx.x * CHUNK;
    for (int k = 0; k < CHUNK / 256; ++k) {
        int e = e0 + threadIdx.x + k * 256;
        if (e < NE) atomicAdd(&h[dst[e] >> 8], 1);
    }
    __syncthreads();
    for (int b = threadIdx.x; b < NBKT; b += 256)
        if (h[b]) atomicAdd(&bcnt[b], h[b]);
}

// ---------- scan of 391 bucket counts -> base & cursor ----------
__global__ void scan_buckets_kernel(const int* __restrict__ bcnt, int* __restrict__ bbase,
                                    int* __restrict__ bcur) {
    __shared__ int s[512];
    int tid = threadIdx.x;
    int v = (tid < NBKT) ? bcnt[tid] : 0;
    s[tid] = v;
    __syncthreads();
    for (int off = 1; off < 512; off <<= 1) {
        int t = (tid >= off) ? s[tid - off] : 0;
        __syncthreads();
        s[tid] += t;
        __syncthreads();
    }
    if (tid < NBKT) { int ex = s[tid] - v; bbase[tid] = ex; bcur[tid] = ex; }
    if (tid == NBKT) bbase[NBKT] = NE;
}

// ---------- phase 1: scatter (src,dst) pairs into block-owned bucket runs ----------
__global__ __launch_bounds__(256) void p1_scatter_kernel(const int* __restrict__ src,
                                                         const int* __restrict__ dst,
                                                         int* __restrict__ bcur,
                                                         int2* __restrict__ gpair) {
    __shared__ int h[NBKT], rb[NBKT], hc[NBKT];
    int tid = threadIdx.x;
    for (int b = tid; b < NBKT; b += 256) { h[b] = 0; hc[b] = 0; }
    __syncthreads();
    int e0 = blockIdx.x * CHUNK;
    for (int k = 0; k < CHUNK / 256; ++k) {
        int e = e0 + tid + k * 256;
        if (e < NE) atomicAdd(&h[dst[e] >> 8], 1);
    }
    __syncthreads();
    for (int b = tid; b < NBKT; b += 256)
        rb[b] = h[b] ? atomicAdd(&bcur[b], h[b]) : 0;   // reserve block-private run
    __syncthreads();
    for (int k = 0; k < CHUNK / 256; ++k) {
        int e = e0 + tid + k * 256;
        if (e < NE) {
            int d = dst[e], s = src[e];
            int b = d >> 8;
            int pos = rb[b] + atomicAdd(&hc[b], 1);
            gpair[pos] = make_int2(s, d);
        }
    }
}

// ---------- phase 2: per-bucket place -> csr, row_start, nrm ----------
__global__ __launch_bounds__(256) void p2_place_kernel(const int2* __restrict__ gpair,
                                                       const int* __restrict__ bbase,
                                                       int* __restrict__ csr,
                                                       int* __restrict__ row_start,
                                                       float* __restrict__ nrm) {
    __shared__ int cnt[256], nexcl[256], pcnt[256];
    int b = blockIdx.x, tid = threadIdx.x;
    int s0 = bbase[b], s1 = bbase[b + 1];
    cnt[tid] = 0; pcnt[tid] = 0;
    __syncthreads();
    for (int i = s0 + tid; i < s1; i += 256)
        atomicAdd(&cnt[gpair[i].y & 255], 1);
    __syncthreads();
    int v = cnt[tid];
    nexcl[tid] = v;
    __syncthreads();
    for (int off = 1; off < 256; off <<= 1) {
        int t = (tid >= off) ? nexcl[tid - off] : 0;
        __syncthreads();
        nexcl[tid] += t;
        __syncthreads();
    }
    int ex = nexcl[tid] - v;                 // exclusive within bucket
    int node = (b << 8) + tid;
    if (node < NN) {
        row_start[node] = s0 + ex;
        nrm[node] = rsqrtf(fmaxf((float)v, 1.0f));
    }
    if (b == NBKT - 1 && tid == 0) row_start[NN] = NE;
    nexcl[tid] = s0 + ex;                    // own-slot overwrite, barrier below
    __syncthreads();
    for (int i = s0 + tid; i < s1; i += 256) {
        int2 p = gpair[i];
        int l = p.y & 255;
        int pos = nexcl[l] + atomicAdd(&pcnt[l], 1);
        csr[pos] = p.x;                      // block-owned contiguous window
    }
}

// ---------- degree-sorted node permutation ----------
__global__ void dh_hist_kernel(const int* __restrict__ row_start, int* __restrict__ dhist) {
    int i = blockIdx.x * blockDim.x + threadIdx.x;
    if (i < NN) {
        int d = row_start[i + 1] - row_start[i];
        atomicAdd(&dhist[min(d, 63)], 1);
    }
}

__global__ void dh_scan_kernel(const int* __restrict__ dhist, int* __restrict__ dcur) {
    int tid = threadIdx.x;                   // 64 threads = 1 wave
    int v = dhist[tid];
    int incl = v;
    for (int off = 1; off < 64; off <<= 1) {
        int t = __shfl_up(incl, off);
        if (tid >= off) incl += t;
    }
    dcur[tid] = incl - v;
}

__global__ void perm_fill_kernel(const int* __restrict__ row_start, int* __restrict__ dcur,
                                 int* __restrict__ perm) {
    int i = blockIdx.x * blockDim.x + threadIdx.x;
    if (i < NN) {
        int d = row_start[i + 1] - row_start[i];
        int pos = atomicAdd(&dcur[min(d, 63)], 1);
        perm[pos] = i;
    }
}

// x' = x * nrm[node], float4 (64 floats -> 16 float4 per node)
__global__ void scale_x4_kernel(const float4* __restrict__ x4, const float* __restrict__ nrm,
                                float4* __restrict__ xs4, int total4) {
    int i = blockIdx.x * blockDim.x + threadIdx.x;
    if (i < total4) {
        float nv = nrm[i >> 4];
        float4 v = x4[i];
        v.x *= nv; v.y *= nv; v.z *= nv; v.w *= nv;
        xs4[i] = v;
    }
}

// ---------------- fused gather(float4) + linear + act ----------------
// 4 waves/block; each wave processes 4 similar-degree nodes (perm) concurrently.
// h PRE-SCALED by nrm[src]. out = act(nrm_dst*(agg@W^T)+b) [*nrm_dst if SCALE].
// DUAL: mu|lv heads + fused z' -> zbuf.
template<int IN, int ACT, bool SCALE, bool DUAL>
__global__ __launch_bounds__(256) void gcn_fused_kernel(
        const float* __restrict__ h,
        const float* __restrict__ nrm,
        const int* __restrict__ row_start,
        const int* __restrict__ csr,
        const int* __restrict__ perm,
        const float* __restrict__ Wa, const float* __restrict__ ba,
        const float* __restrict__ Wb, const float* __restrict__ bb,
        float* __restrict__ out, float* __restrict__ out2,
        const float* __restrict__ eps, float* __restrict__ zbuf) {
    __shared__ float Wt[64 * 65];                    // [k][o] stride 65
    __shared__ float bs[64];
    __shared__ __align__(16) float aggS[4][4][IN];

    int tid = threadIdx.x;
    if (DUAL) {
        for (int i = tid; i < 32 * 64; i += 256) {   // Wa/Wb are [32][64]
            int o = i >> 6, k = i & 63;
            Wt[k * 65 + o]      = Wa[i];
            Wt[k * 65 + o + 32] = Wb[i];
        }
        if (tid < 32) { bs[tid] = ba[tid]; bs[tid + 32] = bb[tid]; }
    } else {
        for (int i = tid; i < 64 * IN; i += 256) {   // Wa is [64][IN]
            int o = i / IN, k = i % IN;
            Wt[k * 65 + o] = Wa[i];
        }
        if (tid < 64) bs[tid] = ba[tid];
    }
    __syncthreads();

    constexpr int RL  = IN / 4;        // lanes per row (16 or 8)
    constexpr int EPI = 64 / RL;       // edges per iteration (4 or 8)
    int wave = tid >> 6, lane = tid & 63;
    int row_slot = lane / RL;
    int f4 = lane % RL;
    int nb = (blockIdx.x * 4 + wave) * 4;

    const float4* h4 = (const float4*)h;

    int nodes[4], rs[4], re[4];
#pragma unroll
    for (int i = 0; i < 4; ++i) {
        nodes[i] = perm[nb + i];
        rs[i] = row_start[nodes[i]];
        re[i] = row_start[nodes[i] + 1];
    }
    int maxd = max(max(re[0] - rs[0], re[1] - rs[1]), max(re[2] - rs[2], re[3] - rs[3]));

    float4 acc[4];
#pragma unroll
    for (int i = 0; i < 4; ++i) acc[i] = make_float4(0.f, 0.f, 0.f, 0.f);

    for (int t = 0; t < maxd; t += EPI) {
#pragma unroll
        for (int i = 0; i < 4; ++i) {
            int jj = rs[i] + t + row_slot;
            if (jj < re[i]) {                 // exec-masked: no junk traffic
                int s = csr[jj];
                float4 v = h4[(size_t)s * RL + f4];
                acc[i].x += v.x; acc[i].y += v.y; acc[i].z += v.z; acc[i].w += v.w;
            }
        }
    }

#pragma unroll
    for (int i = 0; i < 4; ++i) {
        for (int o = RL; o < 64; o <<= 1) {
            acc[i].x += __shfl_xor(acc[i].x, o);
            acc[i].y += __shfl_xor(acc[i].y, o);
            acc[i].z += __shfl_xor(acc[i].z, o);
            acc[i].w += __shfl_xor(acc[i].w, o);
        }
    }

    if (row_slot == 0) {
#pragma unroll
        for (int i = 0; i < 4; ++i)
            ((float4*)aggS[wave][i])[f4] = acc[i];
    }
    // intra-wave LDS write->read; compiler inserts lgkmcnt wait

#pragma unroll
    for (int i = 0; i < 4; ++i) {
        int node = nodes[i];
        float oa = 0.f;
#pragma unroll
        for (int k = 0; k < IN; ++k)
            oa = fmaf(aggS[wave][i][k], Wt[k * 65 + lane], oa);
        float nv = nrm[node];
        oa = oa * nv + bs[lane];
        if (ACT == 1) oa = fmaxf(oa, 0.f);
        if (ACT == 2) oa = 1.f / (1.f + expf(-oa));
        if (SCALE) oa *= nv;

        if (DUAL) {
            if (lane < 32) out [(size_t)node * 32 + lane]        = oa;
            else           out2[(size_t)node * 32 + (lane - 32)] = oa;
            float lv_v = __shfl(oa, (lane + 32) & 63);
            if (lane < 32) {
                float e = eps[(size_t)node * 32 + lane];
                zbuf[(size_t)node * 32 + lane] = (e * expf(0.5f * lv_v) + oa) * nv;
            }
        } else {
            out[(size_t)node * 64 + lane] = oa;
        }
    }
}

extern "C" void kernel_launch(void* const* d_in, const int* in_sizes, int n_in,
                              void* d_out, int out_size, void* d_ws, size_t ws_size,
                              hipStream_t stream) {
    const float* x    = (const float*)d_in[0];
    const int*   esrc = (const int*)d_in[1];
    const int*   edst = (const int*)d_in[2];
    const float* eps  = (const float*)d_in[3];
    const float* W1  = (const float*)d_in[4];  const float* b1  = (const float*)d_in[5];
    const float* W2  = (const float*)d_in[6];  const float* b2  = (const float*)d_in[7];
    const float* W31 = (const float*)d_in[8];  const float* b31 = (const float*)d_in[9];
    const float* W32 = (const float*)d_in[10]; const float* b32 = (const float*)d_in[11];
    const float* W4  = (const float*)d_in[12]; const float* b4  = (const float*)d_in[13];
    const float* W5  = (const float*)d_in[14]; const float* b5  = (const float*)d_in[15];
    const float* W6  = (const float*)d_in[16]; const float* b6  = (const float*)d_in[17];

    float* outp  = (float*)d_out;
    float* recon = outp;                        // N*64
    float* mu    = outp + (size_t)NN * 64;      // N*32
    float* lv    = mu   + (size_t)NN * 32;      // N*32

    int* wsI       = (int*)d_ws;
    int* bcnt      = wsI;                       // 392
    int* bbase     = bcnt + 392;                // 392
    int* bcur      = bbase + 392;               // 392
    int* row_start = bcur + 392;                // NN+1 (100001) -> pad 3
    int* dhist     = row_start + NN + 4;        // 64
    int* dcur      = dhist + 64;                // 64
    int* perm      = dcur + 64;                 // NN
    int* csr       = perm + NN;                 // NE
    float* nrm     = (float*)(csr + NE);        // NN
    float* hA      = nrm + NN;                  // NN*64, 16B-aligned
    float* hB      = hA + (size_t)NN * 64;      // NN*64
    int2* gpair    = (int2*)hA;                 // aliased: used only before scale_x4

    const int SB = 256;
    const int ngrid = (NN + SB - 1) / SB;       // 391
    const int fgrid = NN / 16;                  // 6250

    // ---- CSR build: bucket counting sort ----
    hipMemsetAsync(bcnt, 0, 392 * sizeof(int), stream);
    hipMemsetAsync(dhist, 0, 64 * sizeof(int), stream);
    p0_hist_kernel<<<NB1, 256, 0, stream>>>(edst, bcnt);
    scan_buckets_kernel<<<1, 512, 0, stream>>>(bcnt, bbase, bcur);
    p1_scatter_kernel<<<NB1, 256, 0, stream>>>(esrc, edst, bcur, gpair);
    p2_place_kernel<<<NBKT, 256, 0, stream>>>(gpair, bbase, csr, row_start, nrm);

    // ---- degree-sorted permutation ----
    dh_hist_kernel<<<ngrid, SB, 0, stream>>>(row_start, dhist);
    dh_scan_kernel<<<1, 64, 0, stream>>>(dhist, dcur);
    perm_fill_kernel<<<ngrid, SB, 0, stream>>>(row_start, dcur, perm);

    // ---- pre-scale input (overwrites hA; gpair no longer needed) ----
    scale_x4_kernel<<<(NN * 16 + SB - 1) / SB, SB, 0, stream>>>((const float4*)x, nrm, (float4*)hA, NN * 16);

    // ---- layers ----
    gcn_fused_kernel<64, 1, true,  false><<<fgrid, 256, 0, stream>>>(hA, nrm, row_start, csr, perm, W1,  b1,  nullptr, nullptr, hB,    nullptr, nullptr, nullptr);
    gcn_fused_kernel<64, 1, true,  false><<<fgrid, 256, 0, stream>>>(hB, nrm, row_start, csr, perm, W2,  b2,  nullptr, nullptr, hA,    nullptr, nullptr, nullptr);
    gcn_fused_kernel<64, 0, false, true ><<<fgrid, 256, 0, stream>>>(hA, nrm, row_start, csr, perm, W31, b31, W32,     b32,     mu,    lv,      eps,     hB);
    gcn_fused_kernel<32, 1, true,  false><<<fgrid, 256, 0, stream>>>(hB, nrm, row_start, csr, perm, W4,  b4,  nullptr, nullptr, hA,    nullptr, nullptr, nullptr);
    gcn_fused_kernel<64, 1, true,  false><<<fgrid, 256, 0, stream>>>(hA, nrm, row_start, csr, perm, W5,  b5,  nullptr, nullptr, hB,    nullptr, nullptr, nullptr);
    gcn_fused_kernel<64, 2, false, false><<<fgrid, 256, 0, stream>>>(hB, nrm, row_start, csr, perm, W6,  b6,  nullptr, nullptr, recon, nullptr, nullptr, nullptr);
}

// Round 5
// 883.312 us; speedup vs baseline: 1.6571x; 1.6571x over previous
//
#include <hip/hip_runtime.h>
#include <math.h>

#define NN 100000
#define NE 1600000
#define NBKT 391                       // ceil(NN/256) buckets of 256 nodes
#define CHUNK 8192
#define NB1 ((NE + CHUNK - 1) / CHUNK) // 196 blocks

// ---------- phase 0: coarse bucket histogram (LDS-privatized) ----------
__global__ __launch_bounds__(256) void p0_hist_kernel(const int* __restrict__ dst,
                                                      int* __restrict__ bcnt) {
    __shared__ int h[NBKT];
    for (int b = threadIdx.x; b < NBKT; b += 256) h[b] = 0;
    __syncthreads();
    int e0 = blockIdx.x * CHUNK;
    for (int k = 0; k < CHUNK / 256; ++k) {
        int e = e0 + threadIdx.x + k * 256;
        if (e < NE) atomicAdd(&h[dst[e] >> 8], 1);
    }
    __syncthreads();
    for (int b = threadIdx.x; b < NBKT; b += 256)
        if (h[b]) atomicAdd(&bcnt[b], h[b]);
}

// ---------- scan of 391 bucket counts -> base & cursor ----------
__global__ void scan_buckets_kernel(const int* __restrict__ bcnt, int* __restrict__ bbase,
                                    int* __restrict__ bcur) {
    __shared__ int s[512];
    int tid = threadIdx.x;
    int v = (tid < NBKT) ? bcnt[tid] : 0;
    s[tid] = v;
    __syncthreads();
    for (int off = 1; off < 512; off <<= 1) {
        int t = (tid >= off) ? s[tid - off] : 0;
        __syncthreads();
        s[tid] += t;
        __syncthreads();
    }
    if (tid < NBKT) { int ex = s[tid] - v; bbase[tid] = ex; bcur[tid] = ex; }
    if (tid == NBKT) bbase[NBKT] = NE;
}

// ---------- phase 1: scatter (src,dst) pairs into block-owned bucket runs ----------
__global__ __launch_bounds__(256) void p1_scatter_kernel(const int* __restrict__ src,
                                                         const int* __restrict__ dst,
                                                         int* __restrict__ bcur,
                                                         int2* __restrict__ gpair) {
    __shared__ int h[NBKT], rb[NBKT], hc[NBKT];
    int tid = threadIdx.x;
    for (int b = tid; b < NBKT; b += 256) { h[b] = 0; hc[b] = 0; }
    __syncthreads();
    int e0 = blockIdx.x * CHUNK;
    for (int k = 0; k < CHUNK / 256; ++k) {
        int e = e0 + tid + k * 256;
        if (e < NE) atomicAdd(&h[dst[e] >> 8], 1);
    }
    __syncthreads();
    for (int b = tid; b < NBKT; b += 256)
        rb[b] = h[b] ? atomicAdd(&bcur[b], h[b]) : 0;   // reserve block-private run
    __syncthreads();
    for (int k = 0; k < CHUNK / 256; ++k) {
        int e = e0 + tid + k * 256;
        if (e < NE) {
            int d = dst[e], s = src[e];
            int b = d >> 8;
            int pos = rb[b] + atomicAdd(&hc[b], 1);
            gpair[pos] = make_int2(s, d);
        }
    }
}

// ---------- phase 2: per-bucket place -> csr, row_start, nrm ----------
__global__ __launch_bounds__(256) void p2_place_kernel(const int2* __restrict__ gpair,
                                                       const int* __restrict__ bbase,
                                                       int* __restrict__ csr,
                                                       int* __restrict__ row_start,
                                                       float* __restrict__ nrm) {
    __shared__ int cnt[256], nexcl[256], pcnt[256];
    int b = blockIdx.x, tid = threadIdx.x;
    int s0 = bbase[b], s1 = bbase[b + 1];
    cnt[tid] = 0; pcnt[tid] = 0;
    __syncthreads();
    for (int i = s0 + tid; i < s1; i += 256)
        atomicAdd(&cnt[gpair[i].y & 255], 1);
    __syncthreads();
    int v = cnt[tid];
    nexcl[tid] = v;
    __syncthreads();
    for (int off = 1; off < 256; off <<= 1) {
        int t = (tid >= off) ? nexcl[tid - off] : 0;
        __syncthreads();
        nexcl[tid] += t;
        __syncthreads();
    }
    int ex = nexcl[tid] - v;                 // exclusive within bucket
    int node = (b << 8) + tid;
    if (node < NN) {
        row_start[node] = s0 + ex;
        nrm[node] = rsqrtf(fmaxf((float)v, 1.0f));
    }
    if (b == NBKT - 1 && tid == 0) row_start[NN] = NE;
    nexcl[tid] = s0 + ex;                    // own-slot overwrite, barrier below
    __syncthreads();
    for (int i = s0 + tid; i < s1; i += 256) {
        int2 p = gpair[i];
        int l = p.y & 255;
        int pos = nexcl[l] + atomicAdd(&pcnt[l], 1);
        csr[pos] = p.x;                      // block-owned contiguous window
    }
}

// ---------- degree-sorted node permutation (LDS-privatized, low contention) ----------
__global__ __launch_bounds__(256) void dh_hist_kernel(const int* __restrict__ row_start,
                                                      int* __restrict__ dhist) {
    __shared__ int h[64];
    int tid = threadIdx.x;
    if (tid < 64) h[tid] = 0;
    __syncthreads();
    int i = blockIdx.x * 256 + tid;
    if (i < NN) {
        int d = row_start[i + 1] - row_start[i];
        atomicAdd(&h[min(d, 63)], 1);        // LDS atomic
    }
    __syncthreads();
    if (tid < 64 && h[tid]) atomicAdd(&dhist[tid], h[tid]);  // 64 global adds/block
}

__global__ void dh_scan_kernel(const int* __restrict__ dhist, int* __restrict__ dcur) {
    int tid = threadIdx.x;                   // 64 threads = 1 wave
    int v = dhist[tid];
    int incl = v;
    for (int off = 1; off < 64; off <<= 1) {
        int t = __shfl_up(incl, off);
        if (tid >= off) incl += t;
    }
    dcur[tid] = incl - v;
}

// Block reserves one run per bin (25k atomic-returns total, not 100k on 64 addrs).
__global__ __launch_bounds__(256) void perm_fill_kernel(const int* __restrict__ row_start,
                                                        int* __restrict__ dcur,
                                                        int* __restrict__ perm) {
    __shared__ int h[64], base[64], cur[64];
    int tid = threadIdx.x;
    if (tid < 64) { h[tid] = 0; cur[tid] = 0; }
    __syncthreads();
    int i = blockIdx.x * 256 + tid;
    int d = 63;
    if (i < NN) {
        d = min(row_start[i + 1] - row_start[i], 63);
        atomicAdd(&h[d], 1);                 // LDS
    }
    __syncthreads();
    if (tid < 64) base[tid] = h[tid] ? atomicAdd(&dcur[tid], h[tid]) : 0;
    __syncthreads();
    if (i < NN) {
        int pos = base[d] + atomicAdd(&cur[d], 1);   // LDS
        perm[pos] = i;
    }
}

// x' = x * nrm[node], float4 (64 floats -> 16 float4 per node)
__global__ void scale_x4_kernel(const float4* __restrict__ x4, const float* __restrict__ nrm,
                                float4* __restrict__ xs4, int total4) {
    int i = blockIdx.x * blockDim.x + threadIdx.x;
    if (i < total4) {
        float nv = nrm[i >> 4];
        float4 v = x4[i];
        v.x *= nv; v.y *= nv; v.z *= nv; v.w *= nv;
        xs4[i] = v;
    }
}

// ---------------- fused gather(float4) + linear + act ----------------
// 4 waves/block; each wave processes 4 similar-degree nodes (perm) concurrently.
// h PRE-SCALED by nrm[src]. out = act(nrm_dst*(agg@W^T)+b) [*nrm_dst if SCALE].
// DUAL: mu|lv heads + fused z' -> zbuf.
template<int IN, int ACT, bool SCALE, bool DUAL>
__global__ __launch_bounds__(256) void gcn_fused_kernel(
        const float* __restrict__ h,
        const float* __restrict__ nrm,
        const int* __restrict__ row_start,
        const int* __restrict__ csr,
        const int* __restrict__ perm,
        const float* __restrict__ Wa, const float* __restrict__ ba,
        const float* __restrict__ Wb, const float* __restrict__ bb,
        float* __restrict__ out, float* __restrict__ out2,
        const float* __restrict__ eps, float* __restrict__ zbuf) {
    __shared__ float Wt[64 * 65];                    // [k][o] stride 65
    __shared__ float bs[64];
    __shared__ __align__(16) float aggS[4][4][IN];

    int tid = threadIdx.x;
    if (DUAL) {
        for (int i = tid; i < 32 * 64; i += 256) {   // Wa/Wb are [32][64]
            int o = i >> 6, k = i & 63;
            Wt[k * 65 + o]      = Wa[i];
            Wt[k * 65 + o + 32] = Wb[i];
        }
        if (tid < 32) { bs[tid] = ba[tid]; bs[tid + 32] = bb[tid]; }
    } else {
        for (int i = tid; i < 64 * IN; i += 256) {   // Wa is [64][IN]
            int o = i / IN, k = i % IN;
            Wt[k * 65 + o] = Wa[i];
        }
        if (tid < 64) bs[tid] = ba[tid];
    }
    __syncthreads();

    constexpr int RL  = IN / 4;        // lanes per row (16 or 8)
    constexpr int EPI = 64 / RL;       // edges per iteration (4 or 8)
    int wave = tid >> 6, lane = tid & 63;
    int row_slot = lane / RL;
    int f4 = lane % RL;
    int nb = (blockIdx.x * 4 + wave) * 4;

    const float4* h4 = (const float4*)h;

    int nodes[4], rs[4], re[4];
#pragma unroll
    for (int i = 0; i < 4; ++i) {
        nodes[i] = perm[nb + i];
        rs[i] = row_start[nodes[i]];
        re[i] = row_start[nodes[i] + 1];
    }
    int maxd = max(max(re[0] - rs[0], re[1] - rs[1]), max(re[2] - rs[2], re[3] - rs[3]));

    float4 acc[4];
#pragma unroll
    for (int i = 0; i < 4; ++i) acc[i] = make_float4(0.f, 0.f, 0.f, 0.f);

    for (int t = 0; t < maxd; t += EPI) {
#pragma unroll
        for (int i = 0; i < 4; ++i) {
            int jj = rs[i] + t + row_slot;
            if (jj < re[i]) {                 // exec-masked: no junk traffic
                int s = csr[jj];
                float4 v = h4[(size_t)s * RL + f4];
                acc[i].x += v.x; acc[i].y += v.y; acc[i].z += v.z; acc[i].w += v.w;
            }
        }
    }

#pragma unroll
    for (int i = 0; i < 4; ++i) {
        for (int o = RL; o < 64; o <<= 1) {
            acc[i].x += __shfl_xor(acc[i].x, o);
            acc[i].y += __shfl_xor(acc[i].y, o);
            acc[i].z += __shfl_xor(acc[i].z, o);
            acc[i].w += __shfl_xor(acc[i].w, o);
        }
    }

    if (row_slot == 0) {
#pragma unroll
        for (int i = 0; i < 4; ++i)
            ((float4*)aggS[wave][i])[f4] = acc[i];
    }
    // intra-wave LDS write->read; compiler inserts lgkmcnt wait

#pragma unroll
    for (int i = 0; i < 4; ++i) {
        int node = nodes[i];
        float oa = 0.f;
#pragma unroll
        for (int k = 0; k < IN; ++k)
            oa = fmaf(aggS[wave][i][k], Wt[k * 65 + lane], oa);
        float nv = nrm[node];
        oa = oa * nv + bs[lane];
        if (ACT == 1) oa = fmaxf(oa, 0.f);
        if (ACT == 2) oa = 1.f / (1.f + expf(-oa));
        if (SCALE) oa *= nv;

        if (DUAL) {
            if (lane < 32) out [(size_t)node * 32 + lane]        = oa;
            else           out2[(size_t)node * 32 + (lane - 32)] = oa;
            float lv_v = __shfl(oa, (lane + 32) & 63);
            if (lane < 32) {
                float e = eps[(size_t)node * 32 + lane];
                zbuf[(size_t)node * 32 + lane] = (e * expf(0.5f * lv_v) + oa) * nv;
            }
        } else {
            out[(size_t)node * 64 + lane] = oa;
        }
    }
}

extern "C" void kernel_launch(void* const* d_in, const int* in_sizes, int n_in,
                              void* d_out, int out_size, void* d_ws, size_t ws_size,
                              hipStream_t stream) {
    const float* x    = (const float*)d_in[0];
    const int*   esrc = (const int*)d_in[1];
    const int*   edst = (const int*)d_in[2];
    const float* eps  = (const float*)d_in[3];
    const float* W1  = (const float*)d_in[4];  const float* b1  = (const float*)d_in[5];
    const float* W2  = (const float*)d_in[6];  const float* b2  = (const float*)d_in[7];
    const float* W31 = (const float*)d_in[8];  const float* b31 = (const float*)d_in[9];
    const float* W32 = (const float*)d_in[10]; const float* b32 = (const float*)d_in[11];
    const float* W4  = (const float*)d_in[12]; const float* b4  = (const float*)d_in[13];
    const float* W5  = (const float*)d_in[14]; const float* b5  = (const float*)d_in[15];
    const float* W6  = (const float*)d_in[16]; const float* b6  = (const float*)d_in[17];

    float* outp  = (float*)d_out;
    float* recon = outp;                        // N*64
    float* mu    = outp + (size_t)NN * 64;      // N*32
    float* lv    = mu   + (size_t)NN * 32;      // N*32

    int* wsI       = (int*)d_ws;
    int* bcnt      = wsI;                       // 392
    int* bbase     = bcnt + 392;                // 392
    int* bcur      = bbase + 392;               // 392
    int* row_start = bcur + 392;                // NN+1 (100001) -> pad 3
    int* dhist     = row_start + NN + 4;        // 64
    int* dcur      = dhist + 64;                // 64
    int* perm      = dcur + 64;                 // NN
    int* csr       = perm + NN;                 // NE
    float* nrm     = (float*)(csr + NE);        // NN
    float* hA      = nrm + NN;                  // NN*64, 16B-aligned
    float* hB      = hA + (size_t)NN * 64;      // NN*64
    int2* gpair    = (int2*)hA;                 // aliased: used only before scale_x4

    const int SB = 256;
    const int ngrid = (NN + SB - 1) / SB;       // 391
    const int fgrid = NN / 16;                  // 6250

    // ---- CSR build: bucket counting sort ----
    hipMemsetAsync(bcnt, 0, 392 * sizeof(int), stream);
    hipMemsetAsync(dhist, 0, 64 * sizeof(int), stream);
    p0_hist_kernel<<<NB1, 256, 0, stream>>>(edst, bcnt);
    scan_buckets_kernel<<<1, 512, 0, stream>>>(bcnt, bbase, bcur);
    p1_scatter_kernel<<<NB1, 256, 0, stream>>>(esrc, edst, bcur, gpair);
    p2_place_kernel<<<NBKT, 256, 0, stream>>>(gpair, bbase, csr, row_start, nrm);

    // ---- degree-sorted permutation (privatized) ----
    dh_hist_kernel<<<ngrid, 256, 0, stream>>>(row_start, dhist);
    dh_scan_kernel<<<1, 64, 0, stream>>>(dhist, dcur);
    perm_fill_kernel<<<ngrid, 256, 0, stream>>>(row_start, dcur, perm);

    // ---- pre-scale input (overwrites hA; gpair no longer needed) ----
    scale_x4_kernel<<<(NN * 16 + SB - 1) / SB, SB, 0, stream>>>((const float4*)x, nrm, (float4*)hA, NN * 16);

    // ---- layers ----
    gcn_fused_kernel<64, 1, true,  false><<<fgrid, 256, 0, stream>>>(hA, nrm, row_start, csr, perm, W1,  b1,  nullptr, nullptr, hB,    nullptr, nullptr, nullptr);
    gcn_fused_kernel<64, 1, true,  false><<<fgrid, 256, 0, stream>>>(hB, nrm, row_start, csr, perm, W2,  b2,  nullptr, nullptr, hA,    nullptr, nullptr, nullptr);
    gcn_fused_kernel<64, 0, false, true ><<<fgrid, 256, 0, stream>>>(hA, nrm, row_start, csr, perm, W31, b31, W32,     b32,     mu,    lv,      eps,     hB);
    gcn_fused_kernel<32, 1, true,  false><<<fgrid, 256, 0, stream>>>(hB, nrm, row_start, csr, perm, W4,  b4,  nullptr, nullptr, hA,    nullptr, nullptr, nullptr);
    gcn_fused_kernel<64, 1, true,  false><<<fgrid, 256, 0, stream>>>(hA, nrm, row_start, csr, perm, W5,  b5,  nullptr, nullptr, hB,    nullptr, nullptr, nullptr);
    gcn_fused_kernel<64, 2, false, false><<<fgrid, 256, 0, stream>>>(hB, nrm, row_start, csr, perm, W6,  b6,  nullptr, nullptr, recon, nullptr, nullptr, nullptr);
}

// Round 6
// 620.792 us; speedup vs baseline: 2.3579x; 1.4229x over previous
//
#include <hip/hip_runtime.h>
#include <hip/hip_fp16.h>
#include <math.h>

#define NN 100000
#define NE 1600000
#define NBKT 391                       // ceil(NN/256) buckets of 256 nodes
#define CHUNK 8192
#define NB1 ((NE + CHUNK - 1) / CHUNK) // 196 blocks

// ---------- phase 0: coarse bucket histogram (LDS-privatized) ----------
__global__ __launch_bounds__(256) void p0_hist_kernel(const int* __restrict__ dst,
                                                      int* __restrict__ bcnt) {
    __shared__ int h[NBKT];
    for (int b = threadIdx.x; b < NBKT; b += 256) h[b] = 0;
    __syncthreads();
    int e0 = blockIdx.x * CHUNK;
    for (int k = 0; k < CHUNK / 256; ++k) {
        int e = e0 + threadIdx.x + k * 256;
        if (e < NE) atomicAdd(&h[dst[e] >> 8], 1);
    }
    __syncthreads();
    for (int b = threadIdx.x; b < NBKT; b += 256)
        if (h[b]) atomicAdd(&bcnt[b], h[b]);
}

// ---------- scan of 391 bucket counts -> base & cursor ----------
__global__ void scan_buckets_kernel(const int* __restrict__ bcnt, int* __restrict__ bbase,
                                    int* __restrict__ bcur) {
    __shared__ int s[512];
    int tid = threadIdx.x;
    int v = (tid < NBKT) ? bcnt[tid] : 0;
    s[tid] = v;
    __syncthreads();
    for (int off = 1; off < 512; off <<= 1) {
        int t = (tid >= off) ? s[tid - off] : 0;
        __syncthreads();
        s[tid] += t;
        __syncthreads();
    }
    if (tid < NBKT) { int ex = s[tid] - v; bbase[tid] = ex; bcur[tid] = ex; }
    if (tid == NBKT) bbase[NBKT] = NE;
}

// ---------- phase 1: scatter (src,dst) pairs into block-owned bucket runs ----------
__global__ __launch_bounds__(256) void p1_scatter_kernel(const int* __restrict__ src,
                                                         const int* __restrict__ dst,
                                                         int* __restrict__ bcur,
                                                         int2* __restrict__ gpair) {
    __shared__ int h[NBKT], rb[NBKT], hc[NBKT];
    int tid = threadIdx.x;
    for (int b = tid; b < NBKT; b += 256) { h[b] = 0; hc[b] = 0; }
    __syncthreads();
    int e0 = blockIdx.x * CHUNK;
    for (int k = 0; k < CHUNK / 256; ++k) {
        int e = e0 + tid + k * 256;
        if (e < NE) atomicAdd(&h[dst[e] >> 8], 1);
    }
    __syncthreads();
    for (int b = tid; b < NBKT; b += 256)
        rb[b] = h[b] ? atomicAdd(&bcur[b], h[b]) : 0;   // reserve block-private run
    __syncthreads();
    for (int k = 0; k < CHUNK / 256; ++k) {
        int e = e0 + tid + k * 256;
        if (e < NE) {
            int d = dst[e], s = src[e];
            int b = d >> 8;
            int pos = rb[b] + atomicAdd(&hc[b], 1);
            gpair[pos] = make_int2(s, d);
        }
    }
}

// ---------- phase 2: per-bucket place -> csr, row_start, nrm ----------
__global__ __launch_bounds__(256) void p2_place_kernel(const int2* __restrict__ gpair,
                                                       const int* __restrict__ bbase,
                                                       int* __restrict__ csr,
                                                       int* __restrict__ row_start,
                                                       float* __restrict__ nrm) {
    __shared__ int cnt[256], nexcl[256], pcnt[256];
    int b = blockIdx.x, tid = threadIdx.x;
    int s0 = bbase[b], s1 = bbase[b + 1];
    cnt[tid] = 0; pcnt[tid] = 0;
    __syncthreads();
    for (int i = s0 + tid; i < s1; i += 256)
        atomicAdd(&cnt[gpair[i].y & 255], 1);
    __syncthreads();
    int v = cnt[tid];
    nexcl[tid] = v;
    __syncthreads();
    for (int off = 1; off < 256; off <<= 1) {
        int t = (tid >= off) ? nexcl[tid - off] : 0;
        __syncthreads();
        nexcl[tid] += t;
        __syncthreads();
    }
    int ex = nexcl[tid] - v;                 // exclusive within bucket
    int node = (b << 8) + tid;
    if (node < NN) {
        row_start[node] = s0 + ex;
        nrm[node] = rsqrtf(fmaxf((float)v, 1.0f));
    }
    if (b == NBKT - 1 && tid == 0) row_start[NN] = NE;
    nexcl[tid] = s0 + ex;                    // own-slot overwrite, barrier below
    __syncthreads();
    for (int i = s0 + tid; i < s1; i += 256) {
        int2 p = gpair[i];
        int l = p.y & 255;
        int pos = nexcl[l] + atomicAdd(&pcnt[l], 1);
        csr[pos] = p.x;                      // block-owned contiguous window
    }
}

union H4 { uint2 u; __half2 h[2]; };

// x' = fp16(x * nrm[node]); 4 floats in -> 4 halves (8 B) out per thread
__global__ void scale_x_h_kernel(const float4* __restrict__ x4, const float* __restrict__ nrm,
                                 uint2* __restrict__ xs, int total4) {
    int i = blockIdx.x * blockDim.x + threadIdx.x;
    if (i < total4) {
        float nv = nrm[i >> 4];
        float4 v = x4[i];
        H4 w;
        w.h[0] = __floats2half2_rn(v.x * nv, v.y * nv);
        w.h[1] = __floats2half2_rn(v.z * nv, v.w * nv);
        xs[i] = w.u;
    }
}

// ---------------- fused gather(fp16) + linear + act ----------------
// 4 waves/block; each wave processes 4 consecutive nodes concurrently (MLP=4).
// h is fp16, PRE-SCALED by nrm[src]; accumulation fp32.
// Unconditional mask-multiply loads (tail lanes load row csr[0]: L1-broadcast, cheap)
// keep the 4 load chains batched — exec-masked variant serialized them (R5 regression).
// out = act(nrm_dst*(agg@W^T)+b); SCALE => *nrm_dst and fp16 out (next layer's input).
// DUAL: mu|lv fp32 heads + fused z' = fp16((eps*exp(0.5 lv)+mu)*nrm) -> zbuf.
template<int IN, int ACT, bool SCALE, bool DUAL>
__global__ __launch_bounds__(256) void gcn_fused_kernel(
        const __half* __restrict__ h,
        const float* __restrict__ nrm,
        const int* __restrict__ row_start,
        const int* __restrict__ csr,
        const float* __restrict__ Wa, const float* __restrict__ ba,
        const float* __restrict__ Wb, const float* __restrict__ bb,
        void* __restrict__ outv, float* __restrict__ out2,
        const float* __restrict__ eps, __half* __restrict__ zbuf) {
    __shared__ float Wt[64 * 65];                    // [k][o] stride 65
    __shared__ float bs[64];
    __shared__ __align__(16) float aggS[4][4][IN];

    int tid = threadIdx.x;
    if (DUAL) {
        for (int i = tid; i < 32 * 64; i += 256) {   // Wa/Wb are [32][64]
            int o = i >> 6, k = i & 63;
            Wt[k * 65 + o]      = Wa[i];
            Wt[k * 65 + o + 32] = Wb[i];
        }
        if (tid < 32) { bs[tid] = ba[tid]; bs[tid + 32] = bb[tid]; }
    } else {
        for (int i = tid; i < 64 * IN; i += 256) {   // Wa is [64][IN]
            int o = i / IN, k = i % IN;
            Wt[k * 65 + o] = Wa[i];
        }
        if (tid < 64) bs[tid] = ba[tid];
    }
    __syncthreads();

    constexpr int RL  = IN / 4;        // lanes per row: 4 halves (8 B) per lane
    constexpr int EPI = 64 / RL;       // edges per iteration (4 or 8)
    int wave = tid >> 6, lane = tid & 63;
    int row_slot = lane / RL;
    int f4 = lane % RL;
    int nodeBase = (blockIdx.x * 4 + wave) * 4;

    const uint2* hp = (const uint2*)h;

    int rs[4], re[4];
#pragma unroll
    for (int i = 0; i < 4; ++i) {
        rs[i] = row_start[nodeBase + i];
        re[i] = row_start[nodeBase + i + 1];
    }
    int maxd = max(max(re[0] - rs[0], re[1] - rs[1]), max(re[2] - rs[2], re[3] - rs[3]));

    float4 acc[4];
#pragma unroll
    for (int i = 0; i < 4; ++i) acc[i] = make_float4(0.f, 0.f, 0.f, 0.f);

    for (int t = 0; t < maxd; t += EPI) {
#pragma unroll
        for (int i = 0; i < 4; ++i) {
            int jj = rs[i] + t + row_slot;
            bool ok = jj < re[i];
            int s = csr[ok ? jj : 0];
            float m = ok ? 1.f : 0.f;
            H4 v; v.u = hp[(size_t)s * RL + f4];
            float2 f01 = __half22float2(v.h[0]);
            float2 f23 = __half22float2(v.h[1]);
            acc[i].x = fmaf(m, f01.x, acc[i].x);
            acc[i].y = fmaf(m, f01.y, acc[i].y);
            acc[i].z = fmaf(m, f23.x, acc[i].z);
            acc[i].w = fmaf(m, f23.y, acc[i].w);
        }
    }

#pragma unroll
    for (int i = 0; i < 4; ++i) {
        for (int o = RL; o < 64; o <<= 1) {
            acc[i].x += __shfl_xor(acc[i].x, o);
            acc[i].y += __shfl_xor(acc[i].y, o);
            acc[i].z += __shfl_xor(acc[i].z, o);
            acc[i].w += __shfl_xor(acc[i].w, o);
        }
    }

    if (row_slot == 0) {
#pragma unroll
        for (int i = 0; i < 4; ++i)
            ((float4*)aggS[wave][i])[f4] = acc[i];
    }
    // intra-wave LDS write->read; compiler inserts lgkmcnt wait

#pragma unroll
    for (int i = 0; i < 4; ++i) {
        int node = nodeBase + i;
        float oa = 0.f;
#pragma unroll
        for (int k = 0; k < IN; ++k)
            oa = fmaf(aggS[wave][i][k], Wt[k * 65 + lane], oa);
        float nv = nrm[node];
        oa = oa * nv + bs[lane];
        if (ACT == 1) oa = fmaxf(oa, 0.f);
        if (ACT == 2) oa = 1.f / (1.f + expf(-oa));

        if (DUAL) {
            float* mu_p = (float*)outv;
            if (lane < 32) mu_p[(size_t)node * 32 + lane]        = oa;
            else           out2[(size_t)node * 32 + (lane - 32)] = oa;
            float lv_v = __shfl(oa, (lane + 32) & 63);   // lanes<32 receive lv
            if (lane < 32) {
                float e = eps[(size_t)node * 32 + lane];
                zbuf[(size_t)node * 32 + lane] = __float2half((e * expf(0.5f * lv_v) + oa) * nv);
            }
        } else if (SCALE) {
            ((__half*)outv)[(size_t)node * 64 + lane] = __float2half(oa * nv);
        } else {
            ((float*)outv)[(size_t)node * 64 + lane] = oa;
        }
    }
}

extern "C" void kernel_launch(void* const* d_in, const int* in_sizes, int n_in,
                              void* d_out, int out_size, void* d_ws, size_t ws_size,
                              hipStream_t stream) {
    const float* x    = (const float*)d_in[0];
    const int*   esrc = (const int*)d_in[1];
    const int*   edst = (const int*)d_in[2];
    const float* eps  = (const float*)d_in[3];
    const float* W1  = (const float*)d_in[4];  const float* b1  = (const float*)d_in[5];
    const float* W2  = (const float*)d_in[6];  const float* b2  = (const float*)d_in[7];
    const float* W31 = (const float*)d_in[8];  const float* b31 = (const float*)d_in[9];
    const float* W32 = (const float*)d_in[10]; const float* b32 = (const float*)d_in[11];
    const float* W4  = (const float*)d_in[12]; const float* b4  = (const float*)d_in[13];
    const float* W5  = (const float*)d_in[14]; const float* b5  = (const float*)d_in[15];
    const float* W6  = (const float*)d_in[16]; const float* b6  = (const float*)d_in[17];

    float* outp  = (float*)d_out;
    float* recon = outp;                        // N*64
    float* mu    = outp + (size_t)NN * 64;      // N*32
    float* lv    = mu   + (size_t)NN * 32;      // N*32

    int* wsI       = (int*)d_ws;
    int* bcnt      = wsI;                       // 392
    int* bbase     = bcnt + 392;                // 392
    int* bcur      = bbase + 392;               // 392
    int* row_start = bcur + 392;                // NN+1, pad to NN+4
    int* csr       = row_start + NN + 4;        // NE
    float* nrm     = (float*)(csr + NE);        // NN
    __half* hA     = (__half*)(nrm + NN);       // NN*64 halves (12.8 MB), 16B-aligned
    __half* hB     = hA + (size_t)NN * 64;      // NN*64 halves
    int2* gpair    = (int2*)hA;                 // aliased: dead after scale_x_h

    const int SB = 256;
    const int fgrid = NN / 16;                  // 6250: 4 waves x 4 nodes

    // ---- CSR build: bucket counting sort ----
    hipMemsetAsync(bcnt, 0, 392 * sizeof(int), stream);
    p0_hist_kernel<<<NB1, 256, 0, stream>>>(edst, bcnt);
    scan_buckets_kernel<<<1, 512, 0, stream>>>(bcnt, bbase, bcur);
    p1_scatter_kernel<<<NB1, 256, 0, stream>>>(esrc, edst, bcur, gpair);
    p2_place_kernel<<<NBKT, 256, 0, stream>>>(gpair, bbase, csr, row_start, nrm);

    // ---- pre-scale input to fp16 (overwrites hA; gpair dead) ----
    scale_x_h_kernel<<<(NN * 16 + SB - 1) / SB, SB, 0, stream>>>((const float4*)x, nrm, (uint2*)hA, NN * 16);

    // ---- layers ----
    gcn_fused_kernel<64, 1, true,  false><<<fgrid, 256, 0, stream>>>(hA, nrm, row_start, csr, W1,  b1,  nullptr, nullptr, hB,    nullptr, nullptr, nullptr);
    gcn_fused_kernel<64, 1, true,  false><<<fgrid, 256, 0, stream>>>(hB, nrm, row_start, csr, W2,  b2,  nullptr, nullptr, hA,    nullptr, nullptr, nullptr);
    // L3 dual: mu/lv -> d_out (fp32), fused z' -> hB (fp16, N*32)
    gcn_fused_kernel<64, 0, false, true ><<<fgrid, 256, 0, stream>>>(hA, nrm, row_start, csr, W31, b31, W32,     b32,     mu,    lv,      eps,     hB);
    gcn_fused_kernel<32, 1, true,  false><<<fgrid, 256, 0, stream>>>(hB, nrm, row_start, csr, W4,  b4,  nullptr, nullptr, hA,    nullptr, nullptr, nullptr);
    gcn_fused_kernel<64, 1, true,  false><<<fgrid, 256, 0, stream>>>(hA, nrm, row_start, csr, W5,  b5,  nullptr, nullptr, hB,    nullptr, nullptr, nullptr);
    gcn_fused_kernel<64, 2, false, false><<<fgrid, 256, 0, stream>>>(hB, nrm, row_start, csr, W6,  b6,  nullptr, nullptr, recon, nullptr, nullptr, nullptr);
}

// Round 7
// 618.067 us; speedup vs baseline: 2.3683x; 1.0044x over previous
//
#include <hip/hip_runtime.h>
#include <hip/hip_fp16.h>
#include <math.h>

#define NN 100000
#define NE 1600000
#define NBKT 391                       // ceil(NN/256) buckets of 256 nodes
#define CHUNK 8192
#define NB1 ((NE + CHUNK - 1) / CHUNK) // 196 blocks

// ---------- phase 0: coarse bucket histogram (LDS-privatized) ----------
__global__ __launch_bounds__(256) void p0_hist_kernel(const int* __restrict__ dst,
                                                      int* __restrict__ bcnt) {
    __shared__ int h[NBKT];
    for (int b = threadIdx.x; b < NBKT; b += 256) h[b] = 0;
    __syncthreads();
    int e0 = blockIdx.x * CHUNK;
    for (int k = 0; k < CHUNK / 256; ++k) {
        int e = e0 + threadIdx.x + k * 256;
        if (e < NE) atomicAdd(&h[dst[e] >> 8], 1);
    }
    __syncthreads();
    for (int b = threadIdx.x; b < NBKT; b += 256)
        if (h[b]) atomicAdd(&bcnt[b], h[b]);
}

// ---------- scan of 391 bucket counts -> base & cursor ----------
__global__ void scan_buckets_kernel(const int* __restrict__ bcnt, int* __restrict__ bbase,
                                    int* __restrict__ bcur) {
    __shared__ int s[512];
    int tid = threadIdx.x;
    int v = (tid < NBKT) ? bcnt[tid] : 0;
    s[tid] = v;
    __syncthreads();
    for (int off = 1; off < 512; off <<= 1) {
        int t = (tid >= off) ? s[tid - off] : 0;
        __syncthreads();
        s[tid] += t;
        __syncthreads();
    }
    if (tid < NBKT) { int ex = s[tid] - v; bbase[tid] = ex; bcur[tid] = ex; }
    if (tid == NBKT) bbase[NBKT] = NE;
}

// ---------- phase 1: scatter packed (src<<8 | dst&255) into bucket runs ----------
// src < 2^17, local dst 8 bits -> 25 bits, fits int; halves gpair traffic vs int2.
__global__ __launch_bounds__(256) void p1_scatter_kernel(const int* __restrict__ src,
                                                         const int* __restrict__ dst,
                                                         int* __restrict__ bcur,
                                                         int* __restrict__ gpair) {
    __shared__ int h[NBKT], rb[NBKT], hc[NBKT];
    int tid = threadIdx.x;
    for (int b = tid; b < NBKT; b += 256) { h[b] = 0; hc[b] = 0; }
    __syncthreads();
    int e0 = blockIdx.x * CHUNK;
    for (int k = 0; k < CHUNK / 256; ++k) {
        int e = e0 + tid + k * 256;
        if (e < NE) atomicAdd(&h[dst[e] >> 8], 1);
    }
    __syncthreads();
    for (int b = tid; b < NBKT; b += 256)
        rb[b] = h[b] ? atomicAdd(&bcur[b], h[b]) : 0;   // reserve block-private run
    __syncthreads();
    for (int k = 0; k < CHUNK / 256; ++k) {
        int e = e0 + tid + k * 256;
        if (e < NE) {
            int d = dst[e], s = src[e];
            int b = d >> 8;
            int pos = rb[b] + atomicAdd(&hc[b], 1);
            gpair[pos] = (s << 8) | (d & 255);
        }
    }
}

// ---------- phase 2: per-bucket place -> csr, row_start, nrm ----------
__global__ __launch_bounds__(256) void p2_place_kernel(const int* __restrict__ gpair,
                                                       const int* __restrict__ bbase,
                                                       int* __restrict__ csr,
                                                       int* __restrict__ row_start,
                                                       float* __restrict__ nrm) {
    __shared__ int cnt[256], nexcl[256], pcnt[256];
    int b = blockIdx.x, tid = threadIdx.x;
    int s0 = bbase[b], s1 = bbase[b + 1];
    cnt[tid] = 0; pcnt[tid] = 0;
    __syncthreads();
    for (int i = s0 + tid; i < s1; i += 256)
        atomicAdd(&cnt[gpair[i] & 255], 1);
    __syncthreads();
    int v = cnt[tid];
    nexcl[tid] = v;
    __syncthreads();
    for (int off = 1; off < 256; off <<= 1) {
        int t = (tid >= off) ? nexcl[tid - off] : 0;
        __syncthreads();
        nexcl[tid] += t;
        __syncthreads();
    }
    int ex = nexcl[tid] - v;                 // exclusive within bucket
    int node = (b << 8) + tid;
    if (node < NN) {
        row_start[node] = s0 + ex;
        nrm[node] = rsqrtf(fmaxf((float)v, 1.0f));
    }
    if (b == NBKT - 1 && tid == 0) row_start[NN] = NE;
    nexcl[tid] = s0 + ex;                    // own-slot overwrite, barrier below
    __syncthreads();
    for (int i = s0 + tid; i < s1; i += 256) {
        int p = gpair[i];
        int l = p & 255;
        int pos = nexcl[l] + atomicAdd(&pcnt[l], 1);
        csr[pos] = p >> 8;                   // block-owned contiguous window
    }
}

union H4 { uint2 u; __half2 h[2]; };

// x' = fp16(x * nrm[node]); 4 floats in -> 4 halves (8 B) out per thread
__global__ void scale_x_h_kernel(const float4* __restrict__ x4, const float* __restrict__ nrm,
                                 uint2* __restrict__ xs, int total4) {
    int i = blockIdx.x * blockDim.x + threadIdx.x;
    if (i < total4) {
        float nv = nrm[i >> 4];
        float4 v = x4[i];
        H4 w;
        w.h[0] = __floats2half2_rn(v.x * nv, v.y * nv);
        w.h[1] = __floats2half2_rn(v.z * nv, v.w * nv);
        xs[i] = w.u;
    }
}

// ---------------- fused gather(fp16) + linear + act ----------------
// 4 waves/block; each wave processes 8 nodes concurrently (MLP=8: 8 independent
// csr->row load chains in flight). h fp16 PRE-SCALED by nrm[src]; fp32 accumulate.
// Unconditional mask-multiply tail (exec-masking regressed in R5).
// out = act(nrm_dst*(agg@W^T)+b); SCALE => *nrm_dst, fp16 out.
// DUAL: mu|lv fp32 heads + fused z' = fp16((eps*exp(0.5 lv)+mu)*nrm) -> zbuf.
template<int IN, int ACT, bool SCALE, bool DUAL>
__global__ __launch_bounds__(256) void gcn_fused_kernel(
        const __half* __restrict__ h,
        const float* __restrict__ nrm,
        const int* __restrict__ row_start,
        const int* __restrict__ csr,
        const float* __restrict__ Wa, const float* __restrict__ ba,
        const float* __restrict__ Wb, const float* __restrict__ bb,
        void* __restrict__ outv, float* __restrict__ out2,
        const float* __restrict__ eps, __half* __restrict__ zbuf) {
    constexpr int MLP = 8;
    __shared__ float Wt[64 * 65];                    // [k][o] stride 65
    __shared__ float bs[64];
    __shared__ __align__(16) float aggS[4][MLP][IN];

    int tid = threadIdx.x;
    if (DUAL) {
        for (int i = tid; i < 32 * 64; i += 256) {   // Wa/Wb are [32][64]
            int o = i >> 6, k = i & 63;
            Wt[k * 65 + o]      = Wa[i];
            Wt[k * 65 + o + 32] = Wb[i];
        }
        if (tid < 32) { bs[tid] = ba[tid]; bs[tid + 32] = bb[tid]; }
    } else {
        for (int i = tid; i < 64 * IN; i += 256) {   // Wa is [64][IN]
            int o = i / IN, k = i % IN;
            Wt[k * 65 + o] = Wa[i];
        }
        if (tid < 64) bs[tid] = ba[tid];
    }
    __syncthreads();

    constexpr int RL  = IN / 4;        // lanes per row: 4 halves (8 B) per lane
    constexpr int EPI = 64 / RL;       // edges per iteration (4 or 8)
    int wave = tid >> 6, lane = tid & 63;
    int row_slot = lane / RL;
    int f4 = lane % RL;
    int nodeBase = (blockIdx.x * 4 + wave) * MLP;

    const uint2* hp = (const uint2*)h;

    int rsb[MLP], re[MLP];
#pragma unroll
    for (int i = 0; i < MLP; ++i) {
        rsb[i] = row_start[nodeBase + i];
        re[i]  = row_start[nodeBase + i + 1];
    }
    int maxd = 0;
#pragma unroll
    for (int i = 0; i < MLP; ++i) maxd = max(maxd, re[i] - rsb[i]);
#pragma unroll
    for (int i = 0; i < MLP; ++i) rsb[i] += row_slot;   // hoist lane offset

    float4 acc[MLP];
#pragma unroll
    for (int i = 0; i < MLP; ++i) acc[i] = make_float4(0.f, 0.f, 0.f, 0.f);

    for (int t = 0; t < maxd; t += EPI) {
        int s[MLP]; float m[MLP];
#pragma unroll
        for (int i = 0; i < MLP; ++i) {                 // batch: all csr loads
            int jj = rsb[i] + t;
            bool ok = jj < re[i];
            s[i] = csr[ok ? jj : 0];
            m[i] = ok ? 1.f : 0.f;
        }
        H4 v[MLP];
#pragma unroll
        for (int i = 0; i < MLP; ++i)                   // batch: all row loads
            v[i].u = hp[(size_t)s[i] * RL + f4];
#pragma unroll
        for (int i = 0; i < MLP; ++i) {                 // math
            float2 f01 = __half22float2(v[i].h[0]);
            float2 f23 = __half22float2(v[i].h[1]);
            acc[i].x = fmaf(m[i], f01.x, acc[i].x);
            acc[i].y = fmaf(m[i], f01.y, acc[i].y);
            acc[i].z = fmaf(m[i], f23.x, acc[i].z);
            acc[i].w = fmaf(m[i], f23.y, acc[i].w);
        }
    }

#pragma unroll
    for (int i = 0; i < MLP; ++i) {
        for (int o = RL; o < 64; o <<= 1) {
            acc[i].x += __shfl_xor(acc[i].x, o);
            acc[i].y += __shfl_xor(acc[i].y, o);
            acc[i].z += __shfl_xor(acc[i].z, o);
            acc[i].w += __shfl_xor(acc[i].w, o);
        }
    }

    if (row_slot == 0) {
#pragma unroll
        for (int i = 0; i < MLP; ++i)
            ((float4*)aggS[wave][i])[f4] = acc[i];
    }
    // intra-wave LDS write->read; compiler inserts lgkmcnt wait

#pragma unroll
    for (int i = 0; i < MLP; ++i) {
        int node = nodeBase + i;
        float oa = 0.f;
#pragma unroll
        for (int k = 0; k < IN; ++k)
            oa = fmaf(aggS[wave][i][k], Wt[k * 65 + lane], oa);
        float nv = nrm[node];
        oa = oa * nv + bs[lane];
        if (ACT == 1) oa = fmaxf(oa, 0.f);
        if (ACT == 2) oa = 1.f / (1.f + expf(-oa));

        if (DUAL) {
            float* mu_p = (float*)outv;
            if (lane < 32) mu_p[(size_t)node * 32 + lane]        = oa;
            else           out2[(size_t)node * 32 + (lane - 32)] = oa;
            float lv_v = __shfl(oa, (lane + 32) & 63);   // lanes<32 receive lv
            if (lane < 32) {
                float e = eps[(size_t)node * 32 + lane];
                zbuf[(size_t)node * 32 + lane] = __float2half((e * expf(0.5f * lv_v) + oa) * nv);
            }
        } else if (SCALE) {
            ((__half*)outv)[(size_t)node * 64 + lane] = __float2half(oa * nv);
        } else {
            ((float*)outv)[(size_t)node * 64 + lane] = oa;
        }
    }
}

extern "C" void kernel_launch(void* const* d_in, const int* in_sizes, int n_in,
                              void* d_out, int out_size, void* d_ws, size_t ws_size,
                              hipStream_t stream) {
    const float* x    = (const float*)d_in[0];
    const int*   esrc = (const int*)d_in[1];
    const int*   edst = (const int*)d_in[2];
    const float* eps  = (const float*)d_in[3];
    const float* W1  = (const float*)d_in[4];  const float* b1  = (const float*)d_in[5];
    const float* W2  = (const float*)d_in[6];  const float* b2  = (const float*)d_in[7];
    const float* W31 = (const float*)d_in[8];  const float* b31 = (const float*)d_in[9];
    const float* W32 = (const float*)d_in[10]; const float* b32 = (const float*)d_in[11];
    const float* W4  = (const float*)d_in[12]; const float* b4  = (const float*)d_in[13];
    const float* W5  = (const float*)d_in[14]; const float* b5  = (const float*)d_in[15];
    const float* W6  = (const float*)d_in[16]; const float* b6  = (const float*)d_in[17];

    float* outp  = (float*)d_out;
    float* recon = outp;                        // N*64
    float* mu    = outp + (size_t)NN * 64;      // N*32
    float* lv    = mu   + (size_t)NN * 32;      // N*32

    int* wsI       = (int*)d_ws;
    int* bcnt      = wsI;                       // 392
    int* bbase     = bcnt + 392;                // 392
    int* bcur      = bbase + 392;               // 392
    int* row_start = bcur + 392;                // NN+1, pad to NN+4
    int* csr       = row_start + NN + 4;        // NE
    float* nrm     = (float*)(csr + NE);        // NN
    __half* hA     = (__half*)(nrm + NN);       // NN*64 halves (12.8 MB), 16B-aligned
    __half* hB     = hA + (size_t)NN * 64;      // NN*64 halves
    int* gpair     = (int*)hA;                  // aliased: dead after scale_x_h

    const int SB = 256;
    const int fgrid = NN / 32;                  // 3125: 4 waves x 8 nodes

    // ---- CSR build: bucket counting sort ----
    hipMemsetAsync(bcnt, 0, 392 * sizeof(int), stream);
    p0_hist_kernel<<<NB1, 256, 0, stream>>>(edst, bcnt);
    scan_buckets_kernel<<<1, 512, 0, stream>>>(bcnt, bbase, bcur);
    p1_scatter_kernel<<<NB1, 256, 0, stream>>>(esrc, edst, bcur, gpair);
    p2_place_kernel<<<NBKT, 256, 0, stream>>>(gpair, bbase, csr, row_start, nrm);

    // ---- pre-scale input to fp16 (overwrites hA; gpair dead) ----
    scale_x_h_kernel<<<(NN * 16 + SB - 1) / SB, SB, 0, stream>>>((const float4*)x, nrm, (uint2*)hA, NN * 16);

    // ---- layers ----
    gcn_fused_kernel<64, 1, true,  false><<<fgrid, 256, 0, stream>>>(hA, nrm, row_start, csr, W1,  b1,  nullptr, nullptr, hB,    nullptr, nullptr, nullptr);
    gcn_fused_kernel<64, 1, true,  false><<<fgrid, 256, 0, stream>>>(hB, nrm, row_start, csr, W2,  b2,  nullptr, nullptr, hA,    nullptr, nullptr, nullptr);
    // L3 dual: mu/lv -> d_out (fp32), fused z' -> hB (fp16, N*32)
    gcn_fused_kernel<64, 0, false, true ><<<fgrid, 256, 0, stream>>>(hA, nrm, row_start, csr, W31, b31, W32,     b32,     mu,    lv,      eps,     hB);
    gcn_fused_kernel<32, 1, true,  false><<<fgrid, 256, 0, stream>>>(hB, nrm, row_start, csr, W4,  b4,  nullptr, nullptr, hA,    nullptr, nullptr, nullptr);
    gcn_fused_kernel<64, 1, true,  false><<<fgrid, 256, 0, stream>>>(hA, nrm, row_start, csr, W5,  b5,  nullptr, nullptr, hB,    nullptr, nullptr, nullptr);
    gcn_fused_kernel<64, 2, false, false><<<fgrid, 256, 0, stream>>>(hB, nrm, row_start, csr, W6,  b6,  nullptr, nullptr, recon, nullptr, nullptr, nullptr);
}